// Round 8
// baseline (106.755 us; speedup 1.0000x reference)
//
#include <hip/hip_runtime.h>
#include <stdint.h>

// Problem geometry (fixed by setup_inputs)
#define W_ 320
#define H_ 256
#define HW_ (W_ * H_)
#define NS_ 64
#define B_ 2
#define HALF_ (NS_ * HW_)   // 5,242,880 = NS*H*W
#define D_PER 8

// ---------------- 4x4 inverse (Gauss-Jordan, partial pivot) ----------------

__device__ void inv4(const float* m, float* invOut) {
    float a[4][8];
    for (int i = 0; i < 4; i++) {
        for (int j = 0; j < 4; j++) {
            a[i][j] = m[i * 4 + j];
            a[i][j + 4] = (i == j) ? 1.0f : 0.0f;
        }
    }
    for (int c = 0; c < 4; c++) {
        int p = c;
        float best = fabsf(a[c][c]);
        for (int r = c + 1; r < 4; r++) {
            float v = fabsf(a[r][c]);
            if (v > best) { best = v; p = r; }
        }
        if (p != c) {
            for (int j = 0; j < 8; j++) { float tmp = a[c][j]; a[c][j] = a[p][j]; a[p][j] = tmp; }
        }
        float pinv = 1.0f / a[c][c];
        for (int j = 0; j < 8; j++) a[c][j] *= pinv;
        for (int r = 0; r < 4; r++) {
            if (r == c) continue;
            float f = a[r][c];
            for (int j = 0; j < 8; j++) a[r][j] -= f * a[c][j];
        }
    }
    for (int i = 0; i < 4; i++)
        for (int j = 0; j < 4; j++) invOut[i * 4 + j] = a[i][j + 4];
}

// ---------------- RNG ----------------

__device__ __forceinline__ float u01(uint32_t b) {
    b = (b >> 9) | 0x3F800000u;
    return __uint_as_float(b) - 1.0f;
}

#define TF_ROUND(r) { x0 += x1; x1 = (x1 << (r)) | (x1 >> (32 - (r))); x1 ^= x0; }

// Threefry-2x32-20, key=(0,1), partitionable-JAX finalizer (out0 ^ out1)
__device__ __forceinline__ uint32_t threefry20_xor(uint32_t c0, uint32_t c1) {
    const uint32_t ks0 = 0u, ks1 = 1u, ks2 = 0x1BD11BDAu ^ ks0 ^ ks1;
    uint32_t x0 = c0 + ks0;
    uint32_t x1 = c1 + ks1;
    TF_ROUND(13) TF_ROUND(15) TF_ROUND(26) TF_ROUND(6)
    x0 += ks1; x1 += ks2 + 1u;
    TF_ROUND(17) TF_ROUND(29) TF_ROUND(16) TF_ROUND(24)
    x0 += ks2; x1 += ks0 + 2u;
    TF_ROUND(13) TF_ROUND(15) TF_ROUND(26) TF_ROUND(6)
    x0 += ks0; x1 += ks1 + 3u;
    TF_ROUND(17) TF_ROUND(29) TF_ROUND(16) TF_ROUND(24)
    x0 += ks1; x1 += ks2 + 4u;
    TF_ROUND(13) TF_ROUND(15) TF_ROUND(26) TF_ROUND(6)
    x0 += ks2; x1 += ks0 + 5u;
    return x0 ^ x1;
}

// den = inv_max + (noise + d)/64 * (inv_min - inv_max) = 1/depth
__device__ __forceinline__ float noise_den(uint32_t t, float fd) {
    return 0.025f + (u01(threefry20_xor(0u, t)) + fd) * 0.001171875f;
}

// ---------------- general-path helper (planar layout, R2-proven) ----------------

__device__ __forceinline__ void corner(const float* __restrict__ img, float xc, float yc, float wgt,
                                       float& c0, float& c1, float& c2) {
    bool valid = (xc >= 0.0f) & (xc <= (float)(W_ - 1)) & (yc >= 0.0f) & (yc <= (float)(H_ - 1));
    float xcc = fminf(fmaxf(xc, 0.0f), (float)(W_ - 1));
    float ycc = fminf(fmaxf(yc, 0.0f), (float)(H_ - 1));
    int xi = (int)xcc;
    int yi = (int)ycc;
    int off = yi * W_ + xi;
    float wv = valid ? wgt : 0.0f;
    c0 += img[off] * wv;
    c1 += img[HW_ + off] * wv;
    c2 += img[2 * HW_ + off] * wv;
}

__device__ __forceinline__ void proj_sample_s(const float* __restrict__ img, const float* __restrict__ pd,
                                              float depth, float x, float y,
                                              float& c0, float& c1, float& c2) {
    float rx = pd[0] * x + pd[1] * y + pd[2];
    float ry = pd[3] * x + pd[4] * y + pd[5];
    float rz = pd[6] * x + pd[7] * y + pd[8];
    float px_ = rx * depth + pd[9];
    float py_ = ry * depth + pd[10];
    float pz_ = rz * depth + pd[11];
    bool neg = pz_ <= 0.001f;
    float z = neg ? 1.0f : pz_;
    float zi = __builtin_amdgcn_rcpf(z);
    float px = (neg ? (float)W_ : px_) * zi;
    float py = (neg ? (float)H_ : py_) * zi;
    float x0f = floorf(px), y0f = floorf(py);
    float wx1 = px - x0f, wy1 = py - y0f;
    float wx0 = 1.0f - wx1, wy0 = 1.0f - wy1;
    c0 = 0.0f; c1 = 0.0f; c2 = 0.0f;
    corner(img, x0f,        y0f,        wx0 * wy0, c0, c1, c2);
    corner(img, x0f + 1.0f, y0f,        wx1 * wy0, c0, c1, c2);
    corner(img, x0f,        y0f + 1.0f, wx0 * wy1, c0, c1, c2);
    corner(img, x0f + 1.0f, y0f + 1.0f, wx1 * wy1, c0, c1, c2);
}

// ---------------- single fused kernel ----------------
// One dispatch: per-block matrix setup (4 threads -> LDS), then either the
// pure-x-shift fast path (planar 3-tap row sampling, batch-sequential to
// minimize live registers) or the general projective path.

__global__ __launch_bounds__(256) void volume_fused(const float* __restrict__ limg,
                                                    const float* __restrict__ rimg,
                                                    const float* __restrict__ lproj,
                                                    const float* __restrict__ rproj,
                                                    const float* __restrict__ gproj,
                                                    float* __restrict__ out) {
    __shared__ float spd[52];   // 4 sets x 12 matrix + 4 flags

    if (threadIdx.x < 4) {
        int p = threadIdx.x;
        int b = p >> 1;
        int s = p & 1;
        float inv[16];
        inv4(gproj + b * 16, inv);
        const float* sp = (s == 0 ? lproj : rproj) + b * 16;
        float o[12];
        for (int i = 0; i < 3; i++) {
            for (int j = 0; j < 3; j++) {
                float acc = 0.0f;
                for (int k = 0; k < 4; k++) acc += sp[i * 4 + k] * inv[k * 4 + j];
                o[i * 3 + j] = acc;
            }
        }
        for (int i = 0; i < 3; i++) {
            float acc = 0.0f;
            for (int k = 0; k < 4; k++) acc += sp[i * 4 + k] * inv[k * 4 + 3];
            o[9 + i] = acc;
        }
        // fast iff pure x-shift (rot==I, ty==tz==0) and |t0|<100 so the
        // 8-depth disparity span (|t0|*8*0.0011719) stays < 1 px
        const float eps = 1e-4f;
        bool ok = fabsf(o[0] - 1.0f) < eps && fabsf(o[1]) < eps && fabsf(o[2]) < eps &&
                  fabsf(o[3]) < eps && fabsf(o[4] - 1.0f) < eps && fabsf(o[5]) < eps &&
                  fabsf(o[6]) < eps && fabsf(o[7]) < eps && fabsf(o[8] - 1.0f) < eps &&
                  fabsf(o[10]) < eps && fabsf(o[11]) < eps &&
                  fabsf(o[9]) < 100.0f;
        for (int i = 0; i < 12; i++) spd[p * 12 + i] = o[i];
        spd[48 + p] = ok ? 1.0f : 0.0f;
    }
    __syncthreads();

    int u = blockIdx.x * 256 + threadIdx.x;
    if (u >= HALF_ / D_PER) return;
    int pix = u % HW_;
    int dgrp = u / HW_;
    int w = pix % W_;
    int h = pix / W_;
    int d0 = dgrp * D_PER;
    int tbase = d0 * HW_ + pix;

    bool fast = (spd[48] != 0.0f) & (spd[49] != 0.0f) & (spd[50] != 0.0f) & (spd[51] != 0.0f);

    if (fast) {
        int rowp = h * W_;
#pragma unroll
        for (int bb = 0; bb < 2; bb++) {
            const float* L = limg + bb * 3 * HW_;
            const float* R = rimg + bb * 3 * HW_;
            float tl = spd[(bb * 2 + 0) * 12 + 9];
            float tr = spd[(bb * 2 + 1) * 12 + 9];
            uint32_t cbase = (uint32_t)tbase + (uint32_t)bb * (uint32_t)HALF_;

            float den[D_PER];
            // extreme-j noise first (den strictly ascending in j) to place taps
            den[0]         = noise_den(cbase,                                (float)d0);
            den[D_PER - 1] = noise_den(cbase + (uint32_t)((D_PER - 1) * HW_), (float)(d0 + D_PER - 1));

            float dmL = (tl >= 0.0f) ? den[0] : den[D_PER - 1];
            float dmR = (tr >= 0.0f) ? den[0] : den[D_PER - 1];
            float fmL = floorf(tl * dmL);
            float fmR = floorf(tr * dmR);
            int XL = w + (int)fmL;
            int XR = w + (int)fmR;

            // 3 taps x 3 channels per image, zeroed when OOB (== zeros padding)
            float qL[3][3], qR[3][3];
#pragma unroll
            for (int k = 0; k < 3; k++) {
                int xk = XL + k;
                bool v = (unsigned)xk < (unsigned)W_;
                int idx = rowp + min(max(xk, 0), W_ - 1);
                qL[k][0] = v ? L[idx] : 0.0f;
                qL[k][1] = v ? L[HW_ + idx] : 0.0f;
                qL[k][2] = v ? L[2 * HW_ + idx] : 0.0f;
                int xr = XR + k;
                bool vr = (unsigned)xr < (unsigned)W_;
                int idr = rowp + min(max(xr, 0), W_ - 1);
                qR[k][0] = vr ? R[idr] : 0.0f;
                qR[k][1] = vr ? R[HW_ + idr] : 0.0f;
                qR[k][2] = vr ? R[2 * HW_ + idr] : 0.0f;
            }

            // remaining threefry grind in the load shadow
#pragma unroll
            for (int j = 1; j < D_PER - 1; j++)
                den[j] = noise_den(cbase + (uint32_t)(j * HW_), (float)(d0 + j));

            // hat-weight 3-tap lerp per depth, diff, store
#pragma unroll
            for (int j = 0; j < D_PER; j++) {
                float xL = tl * den[j] - fmL;   // in [0,2)
                float xR = tr * den[j] - fmR;
                float wL0 = fmaxf(0.0f, 1.0f - xL);
                float wL1 = 1.0f - fabsf(xL - 1.0f);
                float wL2 = fmaxf(0.0f, xL - 1.0f);
                float wR0 = fmaxf(0.0f, 1.0f - xR);
                float wR1 = 1.0f - fabsf(xR - 1.0f);
                float wR2 = fmaxf(0.0f, xR - 1.0f);
                float s0 = fabsf((qR[0][0] * wR0 + qR[1][0] * wR1 + qR[2][0] * wR2)
                               - (qL[0][0] * wL0 + qL[1][0] * wL1 + qL[2][0] * wL2));
                float s1 = fabsf((qR[0][1] * wR0 + qR[1][1] * wR1 + qR[2][1] * wR2)
                               - (qL[0][1] * wL0 + qL[1][1] * wL1 + qL[2][1] * wL2));
                float s2 = fabsf((qR[0][2] * wR0 + qR[1][2] * wR1 + qR[2][2] * wR2)
                               - (qL[0][2] * wL0 + qL[1][2] * wL1 + qL[2][2] * wL2));
                out[tbase + bb * HALF_ + j * HW_] = s0 + s1 + s2;
            }
        }
    } else {
        // general projective path (planar, R2-proven)
        float fx = (float)w;
        float fy = (float)h;
        float lpd[12], rpd[12];
#pragma unroll
        for (int bb = 0; bb < 2; bb++) {
            const float* L = limg + bb * 3 * HW_;
            const float* R = rimg + bb * 3 * HW_;
#pragma unroll
            for (int i = 0; i < 12; i++) { lpd[i] = spd[(bb * 2) * 12 + i]; rpd[i] = spd[(bb * 2 + 1) * 12 + i]; }
#pragma unroll 2
            for (int j = 0; j < D_PER; j++) {
                int d = d0 + j;
                uint32_t t = (uint32_t)tbase + (uint32_t)(j * HW_) + (uint32_t)bb * (uint32_t)HALF_;
                float fd = (float)d;
                float depth = __builtin_amdgcn_rcpf(0.025f + (u01(threefry20_xor(0u, t)) + fd) * 0.001171875f);
                float l0, l1, l2, r0, r1, r2;
                proj_sample_s(L, lpd, depth, fx, fy, l0, l1, l2);
                proj_sample_s(R, rpd, depth, fx, fy, r0, r1, r2);
                out[tbase + bb * HALF_ + j * HW_] = fabsf(r0 - l0) + fabsf(r1 - l1) + fabsf(r2 - l2);
            }
        }
    }
}

extern "C" void kernel_launch(void* const* d_in, const int* in_sizes, int n_in,
                              void* d_out, int out_size, void* d_ws, size_t ws_size,
                              hipStream_t stream) {
    const float* limg  = (const float*)d_in[0];
    const float* rimg  = (const float*)d_in[1];
    const float* lproj = (const float*)d_in[2];
    const float* rproj = (const float*)d_in[3];
    const float* gproj = (const float*)d_in[4];
    float* out = (float*)d_out;
    (void)d_ws; (void)ws_size;

    // HALF_/D_PER = 655,360 threads = 2560 blocks of 256 exactly
    volume_fused<<<HALF_ / D_PER / 256, 256, 0, stream>>>(limg, rimg, lproj, rproj, gproj, out);
}

// Round 9
// 100.822 us; speedup vs baseline: 1.0589x; 1.0589x over previous
//
#include <hip/hip_runtime.h>
#include <stdint.h>

// Problem geometry (fixed by setup_inputs)
#define W_ 320
#define H_ 256
#define HW_ (W_ * H_)
#define NS_ 64
#define B_ 2
#define HALF_ (NS_ * HW_)   // 5,242,880 = NS*H*W
#define D_PER 16

// ---------------- 4x4 inverse (Gauss-Jordan, partial pivot) ----------------

__device__ void inv4(const float* m, float* invOut) {
    float a[4][8];
    for (int i = 0; i < 4; i++) {
        for (int j = 0; j < 4; j++) {
            a[i][j] = m[i * 4 + j];
            a[i][j + 4] = (i == j) ? 1.0f : 0.0f;
        }
    }
    for (int c = 0; c < 4; c++) {
        int p = c;
        float best = fabsf(a[c][c]);
        for (int r = c + 1; r < 4; r++) {
            float v = fabsf(a[r][c]);
            if (v > best) { best = v; p = r; }
        }
        if (p != c) {
            for (int j = 0; j < 8; j++) { float tmp = a[c][j]; a[c][j] = a[p][j]; a[p][j] = tmp; }
        }
        float pinv = 1.0f / a[c][c];
        for (int j = 0; j < 8; j++) a[c][j] *= pinv;
        for (int r = 0; r < 4; r++) {
            if (r == c) continue;
            float f = a[r][c];
            for (int j = 0; j < 8; j++) a[r][j] -= f * a[c][j];
        }
    }
    for (int i = 0; i < 4; i++)
        for (int j = 0; j < 4; j++) invOut[i * 4 + j] = a[i][j + 4];
}

// ---------------- RNG ----------------

__device__ __forceinline__ float u01(uint32_t b) {
    b = (b >> 9) | 0x3F800000u;
    return __uint_as_float(b) - 1.0f;
}

#define TF_ROUND(r) { x0 += x1; x1 = (x1 << (r)) | (x1 >> (32 - (r))); x1 ^= x0; }

// Threefry-2x32-20, key=(0,1), partitionable-JAX finalizer (out0 ^ out1)
__device__ __forceinline__ uint32_t threefry20_xor(uint32_t c0, uint32_t c1) {
    const uint32_t ks0 = 0u, ks1 = 1u, ks2 = 0x1BD11BDAu ^ ks0 ^ ks1;
    uint32_t x0 = c0 + ks0;
    uint32_t x1 = c1 + ks1;
    TF_ROUND(13) TF_ROUND(15) TF_ROUND(26) TF_ROUND(6)
    x0 += ks1; x1 += ks2 + 1u;
    TF_ROUND(17) TF_ROUND(29) TF_ROUND(16) TF_ROUND(24)
    x0 += ks2; x1 += ks0 + 2u;
    TF_ROUND(13) TF_ROUND(15) TF_ROUND(26) TF_ROUND(6)
    x0 += ks0; x1 += ks1 + 3u;
    TF_ROUND(17) TF_ROUND(29) TF_ROUND(16) TF_ROUND(24)
    x0 += ks1; x1 += ks2 + 4u;
    TF_ROUND(13) TF_ROUND(15) TF_ROUND(26) TF_ROUND(6)
    x0 += ks2; x1 += ks0 + 5u;
    return x0 ^ x1;
}

// den = inv_max + (noise + d)/64 * (inv_min - inv_max) = 1/depth
__device__ __forceinline__ float noise_den(uint32_t t, float fd) {
    return 0.025f + (u01(threefry20_xor(0u, t)) + fd) * 0.001171875f;
}

// ---------------- general-path helper (planar layout, R2-proven) ----------------

__device__ __forceinline__ void corner(const float* __restrict__ img, float xc, float yc, float wgt,
                                       float& c0, float& c1, float& c2) {
    bool valid = (xc >= 0.0f) & (xc <= (float)(W_ - 1)) & (yc >= 0.0f) & (yc <= (float)(H_ - 1));
    float xcc = fminf(fmaxf(xc, 0.0f), (float)(W_ - 1));
    float ycc = fminf(fmaxf(yc, 0.0f), (float)(H_ - 1));
    int xi = (int)xcc;
    int yi = (int)ycc;
    int off = yi * W_ + xi;
    float wv = valid ? wgt : 0.0f;
    c0 += img[off] * wv;
    c1 += img[HW_ + off] * wv;
    c2 += img[2 * HW_ + off] * wv;
}

__device__ __forceinline__ void proj_sample_s(const float* __restrict__ img, const float* __restrict__ pd,
                                              float depth, float x, float y,
                                              float& c0, float& c1, float& c2) {
    float rx = pd[0] * x + pd[1] * y + pd[2];
    float ry = pd[3] * x + pd[4] * y + pd[5];
    float rz = pd[6] * x + pd[7] * y + pd[8];
    float px_ = rx * depth + pd[9];
    float py_ = ry * depth + pd[10];
    float pz_ = rz * depth + pd[11];
    bool neg = pz_ <= 0.001f;
    float z = neg ? 1.0f : pz_;
    float zi = __builtin_amdgcn_rcpf(z);
    float px = (neg ? (float)W_ : px_) * zi;
    float py = (neg ? (float)H_ : py_) * zi;
    float x0f = floorf(px), y0f = floorf(py);
    float wx1 = px - x0f, wy1 = py - y0f;
    float wx0 = 1.0f - wx1, wy0 = 1.0f - wy1;
    c0 = 0.0f; c1 = 0.0f; c2 = 0.0f;
    corner(img, x0f,        y0f,        wx0 * wy0, c0, c1, c2);
    corner(img, x0f + 1.0f, y0f,        wx1 * wy0, c0, c1, c2);
    corner(img, x0f,        y0f + 1.0f, wx0 * wy1, c0, c1, c2);
    corner(img, x0f + 1.0f, y0f + 1.0f, wx1 * wy1, c0, c1, c2);
}

// ---------------- single fused kernel, 16 depths/thread ----------------

__global__ __launch_bounds__(256) void volume_fused16(const float* __restrict__ limg,
                                                      const float* __restrict__ rimg,
                                                      const float* __restrict__ lproj,
                                                      const float* __restrict__ rproj,
                                                      const float* __restrict__ gproj,
                                                      float* __restrict__ out) {
    __shared__ float spd[52];   // 4 sets x 12 matrix + 4 flags

    if (threadIdx.x < 4) {
        int p = threadIdx.x;
        int b = p >> 1;
        int s = p & 1;
        float inv[16];
        inv4(gproj + b * 16, inv);
        const float* sp = (s == 0 ? lproj : rproj) + b * 16;
        float o[12];
        for (int i = 0; i < 3; i++) {
            for (int j = 0; j < 3; j++) {
                float acc = 0.0f;
                for (int k = 0; k < 4; k++) acc += sp[i * 4 + k] * inv[k * 4 + j];
                o[i * 3 + j] = acc;
            }
        }
        for (int i = 0; i < 3; i++) {
            float acc = 0.0f;
            for (int k = 0; k < 4; k++) acc += sp[i * 4 + k] * inv[k * 4 + 3];
            o[9 + i] = acc;
        }
        // fast iff pure x-shift (rot==I, ty==tz==0) and |t0|<53 so the
        // 16-depth disparity span (|t0|*16*0.0011719) stays < 1 px
        const float eps = 1e-4f;
        bool ok = fabsf(o[0] - 1.0f) < eps && fabsf(o[1]) < eps && fabsf(o[2]) < eps &&
                  fabsf(o[3]) < eps && fabsf(o[4] - 1.0f) < eps && fabsf(o[5]) < eps &&
                  fabsf(o[6]) < eps && fabsf(o[7]) < eps && fabsf(o[8] - 1.0f) < eps &&
                  fabsf(o[10]) < eps && fabsf(o[11]) < eps &&
                  fabsf(o[9]) < 53.0f;
        for (int i = 0; i < 12; i++) spd[p * 12 + i] = o[i];
        spd[48 + p] = ok ? 1.0f : 0.0f;
    }
    __syncthreads();

    int u = blockIdx.x * 256 + threadIdx.x;   // grid is exact: HALF_/16/256 blocks
    int pix = u % HW_;
    int dgrp = u / HW_;
    int w = pix % W_;
    int h = pix / W_;
    int d0 = dgrp * D_PER;
    int tbase = d0 * HW_ + pix;

    bool fast = (spd[48] != 0.0f) & (spd[49] != 0.0f) & (spd[50] != 0.0f) & (spd[51] != 0.0f);

    if (fast) {
        int rowp = h * W_;
#pragma unroll
        for (int bb = 0; bb < 2; bb++) {
            const float* L = limg + bb * 3 * HW_;
            const float* R = rimg + bb * 3 * HW_;
            float tl = spd[(bb * 2 + 0) * 12 + 9];
            float tr = spd[(bb * 2 + 1) * 12 + 9];
            uint32_t cbase = (uint32_t)tbase + (uint32_t)bb * (uint32_t)HALF_;

            float den[D_PER];
            // extreme-j noise first: den strictly ascending in j, so the
            // min-disparity endpoint picks the shared 3-tap window
            den[0]          = noise_den(cbase,                                  (float)d0);
            den[D_PER - 1]  = noise_den(cbase + (uint32_t)((D_PER - 1) * HW_),  (float)(d0 + D_PER - 1));

            float dmL = (tl >= 0.0f) ? den[0] : den[D_PER - 1];
            float dmR = (tr >= 0.0f) ? den[0] : den[D_PER - 1];
            float fmL = floorf(tl * dmL);
            float fmR = floorf(tr * dmR);
            int XL = w + (int)fmL;
            int XR = w + (int)fmR;

            // 3 taps x 3 channels per image, zeroed when OOB (== zeros padding)
            float qL[3][3], qR[3][3];
#pragma unroll
            for (int k = 0; k < 3; k++) {
                int xk = XL + k;
                bool v = (unsigned)xk < (unsigned)W_;
                int idx = rowp + min(max(xk, 0), W_ - 1);
                qL[k][0] = v ? L[idx] : 0.0f;
                qL[k][1] = v ? L[HW_ + idx] : 0.0f;
                qL[k][2] = v ? L[2 * HW_ + idx] : 0.0f;
                int xr = XR + k;
                bool vr = (unsigned)xr < (unsigned)W_;
                int idr = rowp + min(max(xr, 0), W_ - 1);
                qR[k][0] = vr ? R[idr] : 0.0f;
                qR[k][1] = vr ? R[HW_ + idr] : 0.0f;
                qR[k][2] = vr ? R[2 * HW_ + idr] : 0.0f;
            }

            // remaining threefry grind in the load shadow
#pragma unroll
            for (int j = 1; j < D_PER - 1; j++)
                den[j] = noise_den(cbase + (uint32_t)(j * HW_), (float)(d0 + j));

            // delta-form taps: res = q1 + |t| * (t<0 ? (q0-q1) : (q2-q1)), t = x-1
            float dAL[3], dBL[3], dAR[3], dBR[3];
#pragma unroll
            for (int c = 0; c < 3; c++) {
                dAL[c] = qL[0][c] - qL[1][c];
                dBL[c] = qL[2][c] - qL[1][c];
                dAR[c] = qR[0][c] - qR[1][c];
                dBR[c] = qR[2][c] - qR[1][c];
            }
            float gL = -(fmL + 1.0f);
            float gR = -(fmR + 1.0f);

#pragma unroll
            for (int j = 0; j < D_PER; j++) {
                float tL = fmaf(tl, den[j], gL);    // x-1 in [-1,1)
                float tR = fmaf(tr, den[j], gR);
                float aL = fabsf(tL);
                float aR = fabsf(tR);
                bool nL = tL < 0.0f;
                bool nR = tR < 0.0f;
                float r0 = fmaf(aR, nR ? dAR[0] : dBR[0], qR[1][0]) - fmaf(aL, nL ? dAL[0] : dBL[0], qL[1][0]);
                float r1 = fmaf(aR, nR ? dAR[1] : dBR[1], qR[1][1]) - fmaf(aL, nL ? dAL[1] : dBL[1], qL[1][1]);
                float r2 = fmaf(aR, nR ? dAR[2] : dBR[2], qR[1][2]) - fmaf(aL, nL ? dAL[2] : dBL[2], qL[1][2]);
                out[tbase + bb * HALF_ + j * HW_] = fabsf(r0) + fabsf(r1) + fabsf(r2);
            }
        }
    } else {
        // general projective path (planar, R2-proven)
        float fx = (float)w;
        float fy = (float)h;
        float lpd[12], rpd[12];
#pragma unroll
        for (int bb = 0; bb < 2; bb++) {
            const float* L = limg + bb * 3 * HW_;
            const float* R = rimg + bb * 3 * HW_;
#pragma unroll
            for (int i = 0; i < 12; i++) { lpd[i] = spd[(bb * 2) * 12 + i]; rpd[i] = spd[(bb * 2 + 1) * 12 + i]; }
#pragma unroll 2
            for (int j = 0; j < D_PER; j++) {
                int d = d0 + j;
                uint32_t t = (uint32_t)tbase + (uint32_t)(j * HW_) + (uint32_t)bb * (uint32_t)HALF_;
                float fd = (float)d;
                float depth = __builtin_amdgcn_rcpf(0.025f + (u01(threefry20_xor(0u, t)) + fd) * 0.001171875f);
                float l0, l1, l2, r0, r1, r2;
                proj_sample_s(L, lpd, depth, fx, fy, l0, l1, l2);
                proj_sample_s(R, rpd, depth, fx, fy, r0, r1, r2);
                out[tbase + bb * HALF_ + j * HW_] = fabsf(r0 - l0) + fabsf(r1 - l1) + fabsf(r2 - l2);
            }
        }
    }
}

extern "C" void kernel_launch(void* const* d_in, const int* in_sizes, int n_in,
                              void* d_out, int out_size, void* d_ws, size_t ws_size,
                              hipStream_t stream) {
    const float* limg  = (const float*)d_in[0];
    const float* rimg  = (const float*)d_in[1];
    const float* lproj = (const float*)d_in[2];
    const float* rproj = (const float*)d_in[3];
    const float* gproj = (const float*)d_in[4];
    float* out = (float*)d_out;
    (void)d_ws; (void)ws_size;

    // HALF_/D_PER = 327,680 threads = 1280 blocks of 256 exactly
    volume_fused16<<<HALF_ / D_PER / 256, 256, 0, stream>>>(limg, rimg, lproj, rproj, gproj, out);
}

// Round 10
// 99.595 us; speedup vs baseline: 1.0719x; 1.0123x over previous
//
#include <hip/hip_runtime.h>
#include <stdint.h>

// Problem geometry (fixed by setup_inputs)
#define W_ 320
#define H_ 256
#define HW_ (W_ * H_)
#define NS_ 64
#define B_ 2
#define HALF_ (NS_ * HW_)   // 5,242,880 = NS*H*W
#define D_PER 16

// ---------------- 4x4 inverse (Gauss-Jordan, partial pivot) ----------------

__device__ void inv4(const float* m, float* invOut) {
    float a[4][8];
    for (int i = 0; i < 4; i++) {
        for (int j = 0; j < 4; j++) {
            a[i][j] = m[i * 4 + j];
            a[i][j + 4] = (i == j) ? 1.0f : 0.0f;
        }
    }
    for (int c = 0; c < 4; c++) {
        int p = c;
        float best = fabsf(a[c][c]);
        for (int r = c + 1; r < 4; r++) {
            float v = fabsf(a[r][c]);
            if (v > best) { best = v; p = r; }
        }
        if (p != c) {
            for (int j = 0; j < 8; j++) { float tmp = a[c][j]; a[c][j] = a[p][j]; a[p][j] = tmp; }
        }
        float pinv = 1.0f / a[c][c];
        for (int j = 0; j < 8; j++) a[c][j] *= pinv;
        for (int r = 0; r < 4; r++) {
            if (r == c) continue;
            float f = a[r][c];
            for (int j = 0; j < 8; j++) a[r][j] -= f * a[c][j];
        }
    }
    for (int i = 0; i < 4; i++)
        for (int j = 0; j < 4; j++) invOut[i * 4 + j] = a[i][j + 4];
}

// ---------------- RNG ----------------

// guaranteed 1-instruction rotate: v_alignbit_b32(a,b,c) = (b>>c)|(a<<(32-c))
__device__ __forceinline__ uint32_t rotl_hw(uint32_t x, int r) {
    return __builtin_amdgcn_alignbit(x, x, 32 - r);
}

#define TF_ROUND(r) { x0 += x1; x1 = rotl_hw(x1, r); x1 ^= x0; }

// Threefry-2x32-20, key=(0,1), partitionable-JAX finalizer (out0 ^ out1)
__device__ __forceinline__ uint32_t threefry20_xor(uint32_t c0, uint32_t c1) {
    const uint32_t ks0 = 0u, ks1 = 1u, ks2 = 0x1BD11BDAu ^ ks0 ^ ks1;
    uint32_t x0 = c0 + ks0;
    uint32_t x1 = c1 + ks1;
    TF_ROUND(13) TF_ROUND(15) TF_ROUND(26) TF_ROUND(6)
    x0 += ks1; x1 += ks2 + 1u;
    TF_ROUND(17) TF_ROUND(29) TF_ROUND(16) TF_ROUND(24)
    x0 += ks2; x1 += ks0 + 2u;
    TF_ROUND(13) TF_ROUND(15) TF_ROUND(26) TF_ROUND(6)
    x0 += ks0; x1 += ks1 + 3u;
    TF_ROUND(17) TF_ROUND(29) TF_ROUND(16) TF_ROUND(24)
    x0 += ks1; x1 += ks2 + 4u;
    TF_ROUND(13) TF_ROUND(15) TF_ROUND(26) TF_ROUND(6)
    x0 += ks2; x1 += ks0 + 5u;
    return x0 ^ x1;
}

__device__ __forceinline__ float u01(uint32_t b) {
    b = (b >> 9) | 0x3F800000u;
    return __uint_as_float(b) - 1.0f;
}

// den via fused fma: den = f*c + base, f = bitcast in [1,2),
// base = 0.025 + (d-1)*c  (absorbs the -1 and +d); c = 0.015625*0.075
#define DEN_C 0.001171875f
__device__ __forceinline__ float den_fused(uint32_t bits, float base) {
    uint32_t b = (bits >> 9) | 0x3F800000u;
    return fmaf(__uint_as_float(b), DEN_C, base);
}

// ---------------- general-path helper (planar layout, R2-proven) ----------------

__device__ __forceinline__ void corner(const float* __restrict__ img, float xc, float yc, float wgt,
                                       float& c0, float& c1, float& c2) {
    bool valid = (xc >= 0.0f) & (xc <= (float)(W_ - 1)) & (yc >= 0.0f) & (yc <= (float)(H_ - 1));
    float xcc = fminf(fmaxf(xc, 0.0f), (float)(W_ - 1));
    float ycc = fminf(fmaxf(yc, 0.0f), (float)(H_ - 1));
    int xi = (int)xcc;
    int yi = (int)ycc;
    int off = yi * W_ + xi;
    float wv = valid ? wgt : 0.0f;
    c0 += img[off] * wv;
    c1 += img[HW_ + off] * wv;
    c2 += img[2 * HW_ + off] * wv;
}

__device__ __forceinline__ void proj_sample_s(const float* __restrict__ img, const float* __restrict__ pd,
                                              float depth, float x, float y,
                                              float& c0, float& c1, float& c2) {
    float rx = pd[0] * x + pd[1] * y + pd[2];
    float ry = pd[3] * x + pd[4] * y + pd[5];
    float rz = pd[6] * x + pd[7] * y + pd[8];
    float px_ = rx * depth + pd[9];
    float py_ = ry * depth + pd[10];
    float pz_ = rz * depth + pd[11];
    bool neg = pz_ <= 0.001f;
    float z = neg ? 1.0f : pz_;
    float zi = __builtin_amdgcn_rcpf(z);
    float px = (neg ? (float)W_ : px_) * zi;
    float py = (neg ? (float)H_ : py_) * zi;
    float x0f = floorf(px), y0f = floorf(py);
    float wx1 = px - x0f, wy1 = py - y0f;
    float wx0 = 1.0f - wx1, wy0 = 1.0f - wy1;
    c0 = 0.0f; c1 = 0.0f; c2 = 0.0f;
    corner(img, x0f,        y0f,        wx0 * wy0, c0, c1, c2);
    corner(img, x0f + 1.0f, y0f,        wx1 * wy0, c0, c1, c2);
    corner(img, x0f,        y0f + 1.0f, wx0 * wy1, c0, c1, c2);
    corner(img, x0f + 1.0f, y0f + 1.0f, wx1 * wy1, c0, c1, c2);
}

// ---------------- single fused kernel, 16 depths/thread ----------------

__global__ __launch_bounds__(256) void volume_fused16(const float* __restrict__ limg,
                                                      const float* __restrict__ rimg,
                                                      const float* __restrict__ lproj,
                                                      const float* __restrict__ rproj,
                                                      const float* __restrict__ gproj,
                                                      float* __restrict__ out) {
    __shared__ float spd[52];   // 4 sets x 12 matrix + 4 flags

    if (threadIdx.x < 4) {
        int p = threadIdx.x;
        int b = p >> 1;
        int s = p & 1;
        float inv[16];
        inv4(gproj + b * 16, inv);
        const float* sp = (s == 0 ? lproj : rproj) + b * 16;
        float o[12];
        for (int i = 0; i < 3; i++) {
            for (int j = 0; j < 3; j++) {
                float acc = 0.0f;
                for (int k = 0; k < 4; k++) acc += sp[i * 4 + k] * inv[k * 4 + j];
                o[i * 3 + j] = acc;
            }
        }
        for (int i = 0; i < 3; i++) {
            float acc = 0.0f;
            for (int k = 0; k < 4; k++) acc += sp[i * 4 + k] * inv[k * 4 + 3];
            o[9 + i] = acc;
        }
        // fast iff pure x-shift (rot==I, ty==tz==0) and |t0|<53 so the
        // 16-depth disparity span (|t0|*16*0.0011719) stays < 1 px
        const float eps = 1e-4f;
        bool ok = fabsf(o[0] - 1.0f) < eps && fabsf(o[1]) < eps && fabsf(o[2]) < eps &&
                  fabsf(o[3]) < eps && fabsf(o[4] - 1.0f) < eps && fabsf(o[5]) < eps &&
                  fabsf(o[6]) < eps && fabsf(o[7]) < eps && fabsf(o[8] - 1.0f) < eps &&
                  fabsf(o[10]) < eps && fabsf(o[11]) < eps &&
                  fabsf(o[9]) < 53.0f;
        for (int i = 0; i < 12; i++) spd[p * 12 + i] = o[i];
        spd[48 + p] = ok ? 1.0f : 0.0f;
    }
    __syncthreads();

    int u = blockIdx.x * 256 + threadIdx.x;   // grid exact: HALF_/16/256 blocks
    int pix = u % HW_;
    int dgrp = u / HW_;
    int w = pix % W_;
    int h = pix / W_;
    int d0 = dgrp * D_PER;
    int tbase = d0 * HW_ + pix;

    bool fast = (spd[48] != 0.0f) & (spd[49] != 0.0f) & (spd[50] != 0.0f) & (spd[51] != 0.0f);

    if (fast) {
        int rowp = h * W_;
        // wave-uniform den bases: base_j = 0.025 + (d0+j-1)*c
        float base0 = fmaf((float)(d0 - 1), DEN_C, 0.025f);

#pragma unroll
        for (int bb = 0; bb < 2; bb++) {
            const float* L = limg + bb * 3 * HW_;
            const float* R = rimg + bb * 3 * HW_;
            float tl = spd[(bb * 2 + 0) * 12 + 9];
            float tr = spd[(bb * 2 + 1) * 12 + 9];
            uint32_t cbase = (uint32_t)tbase + (uint32_t)bb * (uint32_t)HALF_;

            float den[D_PER];
            // extreme-j noise first: den strictly ascending in j, so the
            // min-disparity endpoint picks the shared 3-tap window
            den[0]         = den_fused(threefry20_xor(0u, cbase), base0);
            den[D_PER - 1] = den_fused(threefry20_xor(0u, cbase + (uint32_t)((D_PER - 1) * HW_)),
                                       fmaf((float)(D_PER - 1), DEN_C, base0));

            float dmL = (tl >= 0.0f) ? den[0] : den[D_PER - 1];
            float dmR = (tr >= 0.0f) ? den[0] : den[D_PER - 1];
            float fmL = floorf(tl * dmL);
            float fmR = floorf(tr * dmR);
            int XL = w + (int)fmL;
            int XR = w + (int)fmR;

            // 3 taps x 3 channels per image, zeroed when OOB (== zeros padding)
            float qL[3][3], qR[3][3];
#pragma unroll
            for (int k = 0; k < 3; k++) {
                int xk = XL + k;
                bool v = (unsigned)xk < (unsigned)W_;
                int idx = rowp + min(max(xk, 0), W_ - 1);
                qL[k][0] = v ? L[idx] : 0.0f;
                qL[k][1] = v ? L[HW_ + idx] : 0.0f;
                qL[k][2] = v ? L[2 * HW_ + idx] : 0.0f;
                int xr = XR + k;
                bool vr = (unsigned)xr < (unsigned)W_;
                int idr = rowp + min(max(xr, 0), W_ - 1);
                qR[k][0] = vr ? R[idr] : 0.0f;
                qR[k][1] = vr ? R[HW_ + idr] : 0.0f;
                qR[k][2] = vr ? R[2 * HW_ + idr] : 0.0f;
            }

            // remaining threefry grind in the load shadow
#pragma unroll
            for (int j = 1; j < D_PER - 1; j++)
                den[j] = den_fused(threefry20_xor(0u, cbase + (uint32_t)(j * HW_)),
                                   fmaf((float)j, DEN_C, base0));

            // delta-form taps: res = q1 + |t| * (t<0 ? (q0-q1) : (q2-q1)), t = x-1
            float dAL[3], dBL[3], dAR[3], dBR[3];
#pragma unroll
            for (int c = 0; c < 3; c++) {
                dAL[c] = qL[0][c] - qL[1][c];
                dBL[c] = qL[2][c] - qL[1][c];
                dAR[c] = qR[0][c] - qR[1][c];
                dBR[c] = qR[2][c] - qR[1][c];
            }
            float gL = -(fmL + 1.0f);
            float gR = -(fmR + 1.0f);

#pragma unroll
            for (int j = 0; j < D_PER; j++) {
                float tL = fmaf(tl, den[j], gL);    // x-1 in [-1,1)
                float tR = fmaf(tr, den[j], gR);
                float aL = fabsf(tL);
                float aR = fabsf(tR);
                bool nL = tL < 0.0f;
                bool nR = tR < 0.0f;
                float r0 = fmaf(aR, nR ? dAR[0] : dBR[0], qR[1][0]) - fmaf(aL, nL ? dAL[0] : dBL[0], qL[1][0]);
                float r1 = fmaf(aR, nR ? dAR[1] : dBR[1], qR[1][1]) - fmaf(aL, nL ? dAL[1] : dBL[1], qL[1][1]);
                float r2 = fmaf(aR, nR ? dAR[2] : dBR[2], qR[1][2]) - fmaf(aL, nL ? dAL[2] : dBL[2], qL[1][2]);
                out[tbase + bb * HALF_ + j * HW_] = fabsf(r0) + fabsf(r1) + fabsf(r2);
            }
        }
    } else {
        // general projective path (planar, R2-proven)
        float fx = (float)w;
        float fy = (float)h;
        float lpd[12], rpd[12];
#pragma unroll
        for (int bb = 0; bb < 2; bb++) {
            const float* L = limg + bb * 3 * HW_;
            const float* R = rimg + bb * 3 * HW_;
#pragma unroll
            for (int i = 0; i < 12; i++) { lpd[i] = spd[(bb * 2) * 12 + i]; rpd[i] = spd[(bb * 2 + 1) * 12 + i]; }
#pragma unroll 2
            for (int j = 0; j < D_PER; j++) {
                int d = d0 + j;
                uint32_t t = (uint32_t)tbase + (uint32_t)(j * HW_) + (uint32_t)bb * (uint32_t)HALF_;
                float fd = (float)d;
                float depth = __builtin_amdgcn_rcpf(0.025f + (u01(threefry20_xor(0u, t)) + fd) * 0.015625f * 0.075f);
                float l0, l1, l2, r0, r1, r2;
                proj_sample_s(L, lpd, depth, fx, fy, l0, l1, l2);
                proj_sample_s(R, rpd, depth, fx, fy, r0, r1, r2);
                out[tbase + bb * HALF_ + j * HW_] = fabsf(r0 - l0) + fabsf(r1 - l1) + fabsf(r2 - l2);
            }
        }
    }
}

extern "C" void kernel_launch(void* const* d_in, const int* in_sizes, int n_in,
                              void* d_out, int out_size, void* d_ws, size_t ws_size,
                              hipStream_t stream) {
    const float* limg  = (const float*)d_in[0];
    const float* rimg  = (const float*)d_in[1];
    const float* lproj = (const float*)d_in[2];
    const float* rproj = (const float*)d_in[3];
    const float* gproj = (const float*)d_in[4];
    float* out = (float*)d_out;
    (void)d_ws; (void)ws_size;

    // HALF_/D_PER = 327,680 threads = 1280 blocks of 256 exactly
    volume_fused16<<<HALF_ / D_PER / 256, 256, 0, stream>>>(limg, rimg, lproj, rproj, gproj, out);
}